// Round 3
// baseline (113.154 us; speedup 1.0000x reference)
//
#include <hip/hip_runtime.h>
#include <cmath>

typedef float f32x4 __attribute__((ext_vector_type(4)));
typedef float f32x2 __attribute__((ext_vector_type(2)));

#define TT 8192
#define NV 65
#define KTILE 1024
#define SUBK 256
#define NBLK_B 2304  // sum over 512 row-tiles of ceil((16rt+16)/1024)

__device__ __forceinline__ float dot4acc(f32x4 a, f32x4 b, float acc) {
  acc = fmaf(a[0], b[0], acc);
  acc = fmaf(a[1], b[1], acc);
  acc = fmaf(a[2], b[2], acc);
  acc = fmaf(a[3], b[3], acc);
  return acc;
}

// Kernel A: cpt[b*6+e][t] = softmax(embed_w[x])[b,t,e]; also zeroes wsum.
__global__ __launch_bounds__(256) void cp_kernel(const int* __restrict__ x,
                                                 const float* __restrict__ ew,
                                                 float* __restrict__ cpt,
                                                 float* __restrict__ wsum) {
  int n = blockIdx.x * 256 + threadIdx.x;  // n = b*8192 + t
  int b = n >> 13, t = n & 8191;
  int xv = x[n];
  float v[6];
#pragma unroll
  for (int e = 0; e < 6; ++e) v[e] = ew[xv * 6 + e];
  float m = v[0];
#pragma unroll
  for (int e = 1; e < 6; ++e) m = fmaxf(m, v[e]);
  float s = 0.f;
#pragma unroll
  for (int e = 0; e < 6; ++e) { v[e] = expf(v[e] - m); s += v[e]; }
  float inv = 1.f / s;
#pragma unroll
  for (int e = 0; e < 6; ++e) cpt[(b * 6 + e) * TT + t] = v[e] * inv;
  // zero wsum: thread n covers wsum_flat[6n..6n+6) ; 6*32768 = 8192*24 exact
  f32x2 z2 = {0.f, 0.f};
#pragma unroll
  for (int i = 0; i < 3; ++i)
    *reinterpret_cast<f32x2*>(&wsum[6 * n + 2 * i]) = z2;
}

// Kernel B: balanced lower-triangle tiles, wsum[t][24] += tril(W)[tile] @ cp.
// Block = 16 rows x 1024 k. Wave = 8 rows x 12 e-cols. Lane = 4 consecutive k.
// No __syncthreads in the k-loop; cp read straight from L2; W nontemporal.
__global__ __launch_bounds__(256, 3) void sticky_B(const float* __restrict__ W,
                                                   const float* __restrict__ cpt,
                                                   float* __restrict__ wsum) {
  __shared__ float ws_lds[16][24];
  const int tid = threadIdx.x;
  const int w = tid >> 6, lane = tid & 63;
  // bid -> (rt, kt): group g = rt/64 has 64 row-tiles x (g+1) k-tiles,
  // cumulative before g = 32*g*(g+1)
  int bid = blockIdx.x;
  int g = 0;
#pragma unroll
  for (int gg = 1; gg < 8; ++gg)
    if (bid >= 32 * gg * (gg + 1)) g = gg;
  int rem = bid - 32 * g * (g + 1);
  int rt = 64 * g + rem / (g + 1);
  int kt = rem % (g + 1);
  const int R = rt * 16;
  const int k0 = kt * KTILE;
  const int rb = R + 8 * (w >> 1);   // this wave's 8 rows
  const int eb = 12 * (w & 1);       // this wave's e-half

  float acc[8][12];
#pragma unroll
  for (int r = 0; r < 8; ++r)
#pragma unroll
    for (int e2 = 0; e2 < 12; ++e2) acc[r][e2] = 0.f;

#pragma unroll 1
  for (int s = 0; s < KTILE / SUBK; ++s) {
    const int kc = k0 + s * SUBK + lane * 4;
    // 8 W rows, nontemporal (don't evict L2-resident cpt). Upper-triangle
    // entries of position_mask are exactly 0 (tril in setup) -> safe over-read.
    const float* wp = &W[(size_t)rb * TT + kc];
    f32x4 wv[8];
#pragma unroll
    for (int r = 0; r < 8; ++r)
      wv[r] = __builtin_nontemporal_load(
          reinterpret_cast<const f32x4*>(wp + (size_t)r * TT));
#pragma unroll
    for (int e2 = 0; e2 < 12; ++e2) {
      f32x4 c = *reinterpret_cast<const f32x4*>(&cpt[(size_t)(eb + e2) * TT + kc]);
#pragma unroll
      for (int r = 0; r < 8; ++r) acc[r][e2] = dot4acc(wv[r], c, acc[r][e2]);
    }
  }

  // reduce the k-split across the 64 lanes
#pragma unroll
  for (int r = 0; r < 8; ++r)
#pragma unroll
    for (int e2 = 0; e2 < 12; ++e2) {
      float v0 = acc[r][e2];
      v0 += __shfl_xor(v0, 1);
      v0 += __shfl_xor(v0, 2);
      v0 += __shfl_xor(v0, 4);
      v0 += __shfl_xor(v0, 8);
      v0 += __shfl_xor(v0, 16);
      v0 += __shfl_xor(v0, 32);
      acc[r][e2] = v0;
    }
  if (lane == 0) {
#pragma unroll
    for (int r = 0; r < 8; ++r)
#pragma unroll
      for (int e2 = 0; e2 < 12; ++e2)
        ws_lds[8 * (w >> 1) + r][eb + e2] = acc[r][e2];
  }
  __syncthreads();
  // 16 rows x 24 cols = 384 entries; 256 threads -> up to 2 each.
  // (round-2 bug: `if (tid < 384)` left entries 256..383 un-added)
  for (int i = tid; i < 384; i += 256) {
    int row = i / 24, col = i - row * 24;
    atomicAdd(&wsum[(R + row) * 24 + col], ws_lds[row][col]);
  }
}

// Kernel C: one thread per output element, out[b][t][v].
__global__ __launch_bounds__(256) void epi_kernel(
    const float* __restrict__ cpt, const float* __restrict__ wsum,
    const float* __restrict__ rtp, const float* __restrict__ tp,
    const float* __restrict__ CT, const float* __restrict__ RT,
    const float* __restrict__ OM, float* __restrict__ out) {
  int n = blockIdx.x * 256 + threadIdx.x;  // exactly 4*8192*65 threads
  int bt = n / NV;
  int v = n - bt * NV;
  int b = bt >> 13, t = bt & 8191;
  float cp6[6], ws6[6];
#pragma unroll
  for (int e = 0; e < 6; ++e) {
    cp6[e] = cpt[(b * 6 + e) * TT + t];
    ws6[e] = wsum[t * 24 + b * 6 + e];
  }
  float score = 0.f;
#pragma unroll
  for (int e = 0; e < 6; ++e) score = fmaf(cp6[e], ws6[e], score);
  float rt = rtp[0];
  float temp = tp[0];
  float z = (score - rt * rt) / (temp * temp);
  float reset = 1.f / (1.f + expf(-z));  // saturates correctly at extremes
  float o = 0.f;
#pragma unroll
  for (int c = 0; c < 6; ++c) {
    float tc = 0.f, rc = 0.f;
#pragma unroll
    for (int e = 0; e < 6; ++e) {
      tc = fmaf(cp6[e], CT[e * 6 + c], tc);
      rc = fmaf(cp6[e], RT[e * 6 + c], rc);
    }
    float nc = reset * rc + (1.f - reset) * tc;
    o = fmaf(nc, OM[c * NV + v], o);
  }
  out[n] = o;
}

extern "C" void kernel_launch(void* const* d_in, const int* in_sizes, int n_in,
                              void* d_out, int out_size, void* d_ws, size_t ws_size,
                              hipStream_t stream) {
  const int* x = (const int*)d_in[0];
  const float* ew = (const float*)d_in[1];
  const float* W = (const float*)d_in[2];
  const float* rtp = (const float*)d_in[3];
  const float* tp = (const float*)d_in[4];
  const float* CT = (const float*)d_in[5];
  const float* RT = (const float*)d_in[6];
  const float* OM = (const float*)d_in[7];
  float* out = (float*)d_out;
  float* cpt = (float*)d_ws;                       // 24*8192 f32 = 786 KB
  float* wsum = (float*)d_ws + 24 * TT;            // 8192*24 f32 = 786 KB

  hipLaunchKernelGGL(cp_kernel, dim3(128), dim3(256), 0, stream, x, ew, cpt, wsum);
  hipLaunchKernelGGL(sticky_B, dim3(NBLK_B), dim3(256), 0, stream, W, cpt, wsum);
  int nout = 4 * TT * NV;  // 2,129,920 = 8320 * 256 exactly
  hipLaunchKernelGGL(epi_kernel, dim3(nout / 256), dim3(256), 0, stream,
                     cpt, wsum, rtp, tp, CT, RT, OM, out);
}